// Round 1
// baseline (1847.387 us; speedup 1.0000x reference)
//
#include <hip/hip_runtime.h>

// Problem constants: B=32, T=256, IN=64, D=128
// Outputs (fp32, concatenated): h_final[32,128] | y[32,256,128] | jacs[256,32,128,128] | dh_dWh[32,128,128,128]
// out offsets: 0, 4096, 1052672, 135270400  (total 202379264)

// ---------- prep: transpose Wh, Wgate (128x128) and Wx (64x128 -> 128x64) ----------
__global__ void prep_kernel(const float* __restrict__ Wh, const float* __restrict__ Wg,
                            const float* __restrict__ Wx,
                            float* __restrict__ whT, float* __restrict__ wgT, float* __restrict__ wxT)
{
    int idx = blockIdx.x * 256 + threadIdx.x;
    if (idx < 16384) {                       // WhT[i][k] = Wh[k][i]
        int k = idx >> 7, i = idx & 127;
        whT[i * 128 + k] = Wh[idx];
    } else if (idx < 32768) {                // WgT[i][k] = Wgate[k][i]
        int r = idx - 16384;
        int k = r >> 7, i = r & 127;
        wgT[i * 128 + k] = Wg[r];
    } else if (idx < 40960) {                // WxT[i][m] = Wx[m][i]
        int r = idx - 32768;
        int m = r >> 7, i = r & 127;
        wxT[i * 64 + m] = Wx[r];
    }
}

// ---------- xw[b,t,i] = sum_m x[b,t,m] * Wx[m,i] ----------
__global__ __launch_bounds__(128) void xw_kernel(const float* __restrict__ x,
                                                 const float* __restrict__ wxT,
                                                 float* __restrict__ xw)
{
    __shared__ float xs[64];
    int bt = blockIdx.x, i = threadIdx.x;
    if (i < 64) xs[i] = x[bt * 64 + i];
    __syncthreads();
    const float* wr = wxT + i * 64;
    float acc = 0.f;
#pragma unroll
    for (int m = 0; m < 64; m += 4) {
        float4 w4 = *(const float4*)(wr + m);
        acc += xs[m] * w4.x + xs[m + 1] * w4.y + xs[m + 2] * w4.z + xs[m + 3] * w4.w;
    }
    xw[bt * 128 + i] = acc;
}

// ---------- sequential scan: one block per batch, thread i owns output lane i ----------
// Weights held in VGPRs (wh[128], wgc[128]); LDS only for h/a exchange.
__global__ __launch_bounds__(128, 1) void scan_kernel(
    const float* __restrict__ xw, const float* __restrict__ h0,
    const float* __restrict__ whT, const float* __restrict__ wgT,
    float* __restrict__ out,
    float* __restrict__ wd, float* __restrict__ wgv, float* __restrict__ wc,
    float* __restrict__ wdF, float* __restrict__ wuF, float* __restrict__ whF)
{
    const int b = blockIdx.x, i = threadIdx.x;
    __shared__ float hbuf[2][128];
    __shared__ float abuf[128];
    float wh[128], wgc[128];
    {
        const float* whr = whT + i * 128;   // column i of Wh
        const float* wgr = wgT + i * 128;   // column i of Wgate
#pragma unroll
        for (int k = 0; k < 128; k += 4) {
            float4 a4 = *(const float4*)(whr + k);
            wh[k] = a4.x; wh[k + 1] = a4.y; wh[k + 2] = a4.z; wh[k + 3] = a4.w;
            float4 b4 = *(const float4*)(wgr + k);
            wgc[k] = b4.x; wgc[k + 1] = b4.y; wgc[k + 2] = b4.z; wgc[k + 3] = b4.w;
        }
    }
    hbuf[0][i] = h0[b * 128 + i];
    __syncthreads();

    const float inv_sqrt2 = 0.70710678118654752f;
    const float inv_sqrt2pi = 0.39894228040143268f;

    for (int t = 0; t < 256; ++t) {
        int p = t & 1;
        float pre = xw[(b * 256 + t) * 128 + i];
        float s0 = 0.f, s1 = 0.f, s2 = 0.f, s3 = 0.f;
#pragma unroll
        for (int k = 0; k < 128; k += 4) {
            float4 h4 = *(const float4*)&hbuf[p][k];
            s0 += h4.x * wh[k];
            s1 += h4.y * wh[k + 1];
            s2 += h4.z * wh[k + 2];
            s3 += h4.w * wh[k + 3];
        }
        pre += (s0 + s1) + (s2 + s3);

        float cdf = 0.5f * (1.0f + erff(pre * inv_sqrt2));
        float a = pre * cdf;                                   // exact gelu
        float dval = cdf + pre * inv_sqrt2pi * expf(-0.5f * pre * pre);  // gelu'

        long tb = (long)(t * 32 + b) * 128 + i;
        wd[tb] = dval;
        abuf[i] = a;
        __syncthreads();                                       // (1) abuf visible

        float r0 = 0.f, r1 = 0.f, r2 = 0.f, r3 = 0.f;
#pragma unroll
        for (int k = 0; k < 128; k += 4) {
            float4 a4 = *(const float4*)&abuf[k];
            r0 += a4.x * wgc[k];
            r1 += a4.y * wgc[k + 1];
            r2 += a4.z * wgc[k + 2];
            r3 += a4.w * wgc[k + 3];
        }
        float sgate = (r0 + r1) + (r2 + r3);
        float g = 1.0f / (1.0f + expf(-sgate));
        float hp = hbuf[p][i];
        float c = (hp - 1.0f) * g * (1.0f - g);
        float hn = g * hp + 1.0f - g;
        hbuf[p ^ 1][i] = hn;
        wgv[tb] = g;
        wc[tb] = c;
        out[4096 + (b * 256 + t) * 128 + i] = hn;              // y
        __syncthreads();                                       // (2) new h visible
    }

    float hfin = hbuf[0][i];                                   // T even -> final state in buf 0
    out[b * 128 + i] = hfin;                                   // h_final
    whF[b * 128 + i] = hfin;

    // extra evaluation at (x_last, h_final) for dh_dWh
    {
        float pre = xw[(b * 256 + 255) * 128 + i];
        float s0 = 0.f, s1 = 0.f, s2 = 0.f, s3 = 0.f;
#pragma unroll
        for (int k = 0; k < 128; k += 4) {
            float4 h4 = *(const float4*)&hbuf[0][k];
            s0 += h4.x * wh[k];
            s1 += h4.y * wh[k + 1];
            s2 += h4.z * wh[k + 2];
            s3 += h4.w * wh[k + 3];
        }
        pre += (s0 + s1) + (s2 + s3);
        float cdf = 0.5f * (1.0f + erff(pre * inv_sqrt2));
        float a = pre * cdf;
        float dval = cdf + pre * inv_sqrt2pi * expf(-0.5f * pre * pre);
        wdF[b * 128 + i] = dval;
        abuf[i] = a;
        __syncthreads();
        float r0 = 0.f, r1 = 0.f, r2 = 0.f, r3 = 0.f;
#pragma unroll
        for (int k = 0; k < 128; k += 4) {
            float4 a4 = *(const float4*)&abuf[k];
            r0 += a4.x * wgc[k];
            r1 += a4.y * wgc[k + 1];
            r2 += a4.z * wgc[k + 2];
            r3 += a4.w * wgc[k + 3];
        }
        float sgate = (r0 + r1) + (r2 + r3);
        float g = 1.0f / (1.0f + expf(-sgate));
        wuF[b * 128 + i] = (hfin - 1.0f) * g * (1.0f - g);
    }
}

// ---------- jacs: one block per (t,b); jac = diag(g) + diag(c) * (Wgate^T diag(d) Wh^T) ----------
__global__ __launch_bounds__(256) void jac_kernel(const float* __restrict__ Wgate,
                                                  const float* __restrict__ whT,
                                                  const float* __restrict__ wd,
                                                  const float* __restrict__ wgv,
                                                  const float* __restrict__ wc,
                                                  float* __restrict__ out)
{
    __shared__ float As[32][132];   // As[kk][i] = Wgate[k][i] * d[k]
    __shared__ float Bs[32][132];   // Bs[kk][j] = Wh[j][k]  (= whT[k][j])
    __shared__ float dl[128];

    int blk = blockIdx.x;
    int t = blk >> 5, b = blk & 31;
    int tid = threadIdx.x;
    int tx = tid & 15, ty = tid >> 4;
    int i0 = ty * 8, j0 = tx * 8;
    long base_tb = (long)(t * 32 + b) * 128;

    if (tid < 128) dl[tid] = wd[base_tb + tid];

    float acc[8][8];
#pragma unroll
    for (int p = 0; p < 8; ++p)
#pragma unroll
        for (int q = 0; q < 8; ++q) acc[p][q] = 0.f;
    __syncthreads();

    for (int kb = 0; kb < 128; kb += 32) {
#pragma unroll
        for (int e = 0; e < 16; ++e) {
            int idx = e * 256 + tid;
            int kk = idx >> 7, ii = idx & 127;
            As[kk][ii] = Wgate[(kb + kk) * 128 + ii] * dl[kb + kk];
            Bs[kk][ii] = whT[(kb + kk) * 128 + ii];
        }
        __syncthreads();
#pragma unroll
        for (int kk = 0; kk < 32; ++kk) {
            float4 a0 = *(const float4*)&As[kk][i0];
            float4 a1 = *(const float4*)&As[kk][i0 + 4];
            float4 b0 = *(const float4*)&Bs[kk][j0];
            float4 b1 = *(const float4*)&Bs[kk][j0 + 4];
            float av[8] = {a0.x, a0.y, a0.z, a0.w, a1.x, a1.y, a1.z, a1.w};
            float bv[8] = {b0.x, b0.y, b0.z, b0.w, b1.x, b1.y, b1.z, b1.w};
#pragma unroll
            for (int p = 0; p < 8; ++p)
#pragma unroll
                for (int q = 0; q < 8; ++q)
                    acc[p][q] += av[p] * bv[q];
        }
        __syncthreads();
    }

    const long jacOff = 1052672L;
#pragma unroll
    for (int p = 0; p < 8; ++p) {
        int irow = i0 + p;
        float ci = wc[base_tb + irow];
        float gi = wgv[base_tb + irow];
        float vals[8];
#pragma unroll
        for (int q = 0; q < 8; ++q) {
            float v = ci * acc[p][q];
            if (j0 + q == irow) v += gi;
            vals[q] = v;
        }
        float4* dst = (float4*)(out + jacOff + (base_tb + irow) * 128 + j0);
        dst[0] = make_float4(vals[0], vals[1], vals[2], vals[3]);
        dst[1] = make_float4(vals[4], vals[5], vals[6], vals[7]);
    }
}

// ---------- dh_dWh[b,i,p,q] = u[b,i] * hF[b,p] * dF[b,q] * Wgate[q,i] ----------
__global__ __launch_bounds__(128) void dhdw_kernel(const float* __restrict__ Wgate,
                                                   const float* __restrict__ dF,
                                                   const float* __restrict__ uF,
                                                   const float* __restrict__ hF,
                                                   float* __restrict__ out)
{
    int blk = blockIdx.x;               // b*128 + i
    int b = blk >> 7, i = blk & 127;
    int q = threadIdx.x;
    float u = uF[b * 128 + i];
    float w = dF[b * 128 + q] * Wgate[q * 128 + i];
    float uw = u * w;
    const float* hrow = hF + b * 128;
    float* dst = out + 135270400L + ((long)(b * 128 + i)) * 16384 + q;
#pragma unroll 4
    for (int p = 0; p < 128; ++p) {
        dst[p * 128] = uw * hrow[p];    // hrow[p] is wave-uniform -> s_load
    }
}

extern "C" void kernel_launch(void* const* d_in, const int* in_sizes, int n_in,
                              void* d_out, int out_size, void* d_ws, size_t ws_size,
                              hipStream_t stream)
{
    (void)in_sizes; (void)n_in; (void)out_size; (void)ws_size;
    const float* x     = (const float*)d_in[0];
    const float* h0    = (const float*)d_in[1];
    const float* Wx    = (const float*)d_in[2];
    const float* Wgate = (const float*)d_in[3];
    const float* Wh    = (const float*)d_in[4];
    float* out = (float*)d_out;
    float* ws  = (float*)d_ws;

    // workspace layout (floats): total ~4.25M floats = 17 MB
    float* xw  = ws;                // 1048576  [b][t][i]
    float* whT = ws + 1048576;      // 16384
    float* wgT = ws + 1064960;      // 16384
    float* wxT = ws + 1081344;      // 8192
    float* wd  = ws + 1089536;      // 1048576  [t][b][k]
    float* wgv = ws + 2138112;      // 1048576
    float* wc  = ws + 3186688;      // 1048576
    float* wdF = ws + 4235264;      // 4096
    float* wuF = ws + 4239360;      // 4096
    float* whF = ws + 4243456;      // 4096

    prep_kernel<<<160, 256, 0, stream>>>(Wh, Wgate, Wx, whT, wgT, wxT);
    xw_kernel<<<8192, 128, 0, stream>>>(x, wxT, xw);
    scan_kernel<<<32, 128, 0, stream>>>(xw, h0, whT, wgT, out, wd, wgv, wc, wdF, wuF, whF);
    jac_kernel<<<8192, 256, 0, stream>>>(Wgate, whT, wd, wgv, wc, out);
    dhdw_kernel<<<4096, 128, 0, stream>>>(Wgate, wdF, wuF, whF, out);
}

// Round 2
// 1349.608 us; speedup vs baseline: 1.3688x; 1.3688x over previous
//
#include <hip/hip_runtime.h>

// Problem constants: B=32, T=256, IN=64, D=128
// Outputs (fp32, concatenated): h_final[32,128] | y[32,256,128] | jacs[256,32,128,128] | dh_dWh[32,128,128,128]
// out offsets: 0, 4096, 1052672, 135270400  (total 202379264)

#define JACOFF 1052672L
#define DHWOFF 135270400L

typedef __attribute__((ext_vector_type(8))) short frag_ab;   // 8 bf16 (4 VGPRs)
typedef __attribute__((ext_vector_type(4))) float frag_cd;   // 4 fp32

__device__ __forceinline__ short f2bf(float f) {
    unsigned u = __builtin_bit_cast(unsigned, f);
    unsigned r = (u + 0x7fffu + ((u >> 16) & 1u)) >> 16;     // RNE
    return (short)r;
}

// ---------- prep: transpose Wh, Wgate (128x128) and Wx (64x128 -> 128x64) ----------
__global__ void prep_kernel(const float* __restrict__ Wh, const float* __restrict__ Wg,
                            const float* __restrict__ Wx,
                            float* __restrict__ whT, float* __restrict__ wgT, float* __restrict__ wxT)
{
    int idx = blockIdx.x * 256 + threadIdx.x;
    if (idx < 16384) {                       // WhT[i][k] = Wh[k][i]
        int k = idx >> 7, i = idx & 127;
        whT[i * 128 + k] = Wh[idx];
    } else if (idx < 32768) {                // WgT[i][k] = Wgate[k][i]
        int r = idx - 16384;
        int k = r >> 7, i = r & 127;
        wgT[i * 128 + k] = Wg[r];
    } else if (idx < 40960) {                // WxT[i][m] = Wx[m][i]
        int r = idx - 32768;
        int m = r >> 7, i = r & 127;
        wxT[i * 64 + m] = Wx[r];
    }
}

// ---------- xw[b,t,i] = sum_m x[b,t,m] * Wx[m,i] ----------
__global__ __launch_bounds__(128) void xw_kernel(const float* __restrict__ x,
                                                 const float* __restrict__ wxT,
                                                 float* __restrict__ xw)
{
    __shared__ float xs[64];
    int bt = blockIdx.x, i = threadIdx.x;
    if (i < 64) xs[i] = x[bt * 64 + i];
    __syncthreads();
    const float* wr = wxT + i * 64;
    float acc = 0.f;
#pragma unroll
    for (int m = 0; m < 64; m += 4) {
        float4 w4 = *(const float4*)(wr + m);
        acc += xs[m] * w4.x + xs[m + 1] * w4.y + xs[m + 2] * w4.z + xs[m + 3] * w4.w;
    }
    xw[bt * 128 + i] = acc;
}

// ---------- PT[col][k] = bf16(Wgate[k][i] * Wh[j][k]),  col = i*128 + j ----------
// 16384 cols x 128 k. Block handles 16 cols; thread: (colofs = tid>>4, kgrp = tid&15).
__global__ __launch_bounds__(256) void pk_kernel(const float* __restrict__ Wgate,
                                                 const float* __restrict__ Wh,
                                                 short* __restrict__ PT)
{
    int tid = threadIdx.x;
    int c = blockIdx.x * 16 + (tid >> 4);
    int k0 = (tid & 15) * 8;
    int i = c >> 7, j = c & 127;
    short v[8];
#pragma unroll
    for (int m = 0; m < 8; ++m) {
        float wg = Wgate[(k0 + m) * 128 + i];
        float wh = Wh[j * 128 + k0 + m];
        v[m] = f2bf(wg * wh);
    }
    *(frag_ab*)(PT + (long)c * 128 + k0) = *(frag_ab*)v;
}

// ---------- sequential scan: one block per batch, thread i owns output lane i ----------
__global__ __launch_bounds__(128, 1) void scan_kernel(
    const float* __restrict__ xw, const float* __restrict__ h0,
    const float* __restrict__ whT, const float* __restrict__ wgT,
    float* __restrict__ out,
    short* __restrict__ Abf, float* __restrict__ wgv, float* __restrict__ wc,
    float* __restrict__ wdF, float* __restrict__ wuF, float* __restrict__ whF)
{
    const int b = blockIdx.x, i = threadIdx.x;
    __shared__ float hbuf[2][128];
    __shared__ float abuf[128];
    float wh[128], wgc[128];
    {
        const float* whr = whT + i * 128;   // column i of Wh
        const float* wgr = wgT + i * 128;   // column i of Wgate
#pragma unroll
        for (int k = 0; k < 128; k += 4) {
            float4 a4 = *(const float4*)(whr + k);
            wh[k] = a4.x; wh[k + 1] = a4.y; wh[k + 2] = a4.z; wh[k + 3] = a4.w;
            float4 b4 = *(const float4*)(wgr + k);
            wgc[k] = b4.x; wgc[k + 1] = b4.y; wgc[k + 2] = b4.z; wgc[k + 3] = b4.w;
        }
    }
    hbuf[0][i] = h0[b * 128 + i];
    __syncthreads();

    const float inv_sqrt2 = 0.70710678118654752f;
    const float inv_sqrt2pi = 0.39894228040143268f;

    for (int t = 0; t < 256; ++t) {
        int p = t & 1;
        float pre = xw[(b * 256 + t) * 128 + i];
        float s0 = 0.f, s1 = 0.f, s2 = 0.f, s3 = 0.f;
#pragma unroll
        for (int k = 0; k < 128; k += 4) {
            float4 h4 = *(const float4*)&hbuf[p][k];
            s0 += h4.x * wh[k];
            s1 += h4.y * wh[k + 1];
            s2 += h4.z * wh[k + 2];
            s3 += h4.w * wh[k + 3];
        }
        pre += (s0 + s1) + (s2 + s3);

        float cdf = 0.5f * (1.0f + erff(pre * inv_sqrt2));
        float a = pre * cdf;                                   // exact gelu
        float dval = cdf + pre * inv_sqrt2pi * expf(-0.5f * pre * pre);  // gelu'

        long tb = (long)(t * 32 + b) * 128 + i;
        Abf[tb] = f2bf(dval);
        abuf[i] = a;
        __syncthreads();                                       // (1) abuf visible

        float r0 = 0.f, r1 = 0.f, r2 = 0.f, r3 = 0.f;
#pragma unroll
        for (int k = 0; k < 128; k += 4) {
            float4 a4 = *(const float4*)&abuf[k];
            r0 += a4.x * wgc[k];
            r1 += a4.y * wgc[k + 1];
            r2 += a4.z * wgc[k + 2];
            r3 += a4.w * wgc[k + 3];
        }
        float sgate = (r0 + r1) + (r2 + r3);
        float g = 1.0f / (1.0f + expf(-sgate));
        float hp = hbuf[p][i];
        float c = (hp - 1.0f) * g * (1.0f - g);
        float hn = g * hp + 1.0f - g;
        hbuf[p ^ 1][i] = hn;
        wgv[tb] = g;
        wc[tb] = c;
        out[4096 + (b * 256 + t) * 128 + i] = hn;              // y
        __syncthreads();                                       // (2) new h visible
    }

    float hfin = hbuf[0][i];                                   // T even -> final state in buf 0
    out[b * 128 + i] = hfin;                                   // h_final
    whF[b * 128 + i] = hfin;

    // extra evaluation at (x_last, h_final) for dh_dWh
    {
        float pre = xw[(b * 256 + 255) * 128 + i];
        float s0 = 0.f, s1 = 0.f, s2 = 0.f, s3 = 0.f;
#pragma unroll
        for (int k = 0; k < 128; k += 4) {
            float4 h4 = *(const float4*)&hbuf[0][k];
            s0 += h4.x * wh[k];
            s1 += h4.y * wh[k + 1];
            s2 += h4.z * wh[k + 2];
            s3 += h4.w * wh[k + 3];
        }
        pre += (s0 + s1) + (s2 + s3);
        float cdf = 0.5f * (1.0f + erff(pre * inv_sqrt2));
        float a = pre * cdf;
        float dval = cdf + pre * inv_sqrt2pi * expf(-0.5f * pre * pre);
        wdF[b * 128 + i] = dval;
        abuf[i] = a;
        __syncthreads();
        float r0 = 0.f, r1 = 0.f, r2 = 0.f, r3 = 0.f;
#pragma unroll
        for (int k = 0; k < 128; k += 4) {
            float4 a4 = *(const float4*)&abuf[k];
            r0 += a4.x * wgc[k];
            r1 += a4.y * wgc[k + 1];
            r2 += a4.z * wgc[k + 2];
            r3 += a4.w * wgc[k + 3];
        }
        float sgate = (r0 + r1) + (r2 + r3);
        float g = 1.0f / (1.0f + expf(-sgate));
        wuF[b * 128 + i] = (hfin - 1.0f) * g * (1.0f - g);
    }
}

// ---------- jacs as one GEMM: C[row=tb][col=i*128+j] = sum_k Abf[row][k] * PT[col][k] ----------
// epilogue: out = c[row, cb]*acc + (j==cb)*g[row, cb], where cb = col block = i.
// 128x128 C-tile per 256-thread block; bf16 MFMA 16x16x32; K=128 single pass.
// LDS tiles stored as XOR-swizzled 16B chunks: chunk(r, ko) lives at index r*16 + (ko ^ (r&15)).
__global__ __launch_bounds__(256) void jacmm_kernel(
    const short* __restrict__ Abf,   // [8192][128] bf16
    const short* __restrict__ PT,    // [16384][128] bf16
    const float* __restrict__ wgv,   // [8192][128]
    const float* __restrict__ wc,    // [8192][128]
    float* __restrict__ out)
{
    __shared__ short Atile[128 * 128];   // 32 KB
    __shared__ short Btile[128 * 128];   // 32 KB

    int bx = blockIdx.x;
    int rb = bx & 63;        // row block: tb in [rb*128, rb*128+128)
    int cb = bx >> 6;        // col block = i (0..127)
    int tid = threadIdx.x;

    const short* Ag = Abf + (long)rb * (128 * 128);
    const short* Bg = PT + (long)cb * (128 * 128);

    // stage both tiles via global_load_lds width=16, swizzled via per-lane global source
#pragma unroll
    for (int e = 0; e < 8; ++e) {
        int q = e * 256 + tid;           // LDS chunk slot 0..2047 (lane-contiguous)
        int r = q >> 4;
        int s = q & 15;
        int ko = s ^ (r & 15);           // which global k-octet lands in this slot
        const short* srcA = Ag + r * 128 + ko * 8;
        const short* srcB = Bg + r * 128 + ko * 8;
        __builtin_amdgcn_global_load_lds(
            (const __attribute__((address_space(1))) void*)srcA,
            (__attribute__((address_space(3))) void*)(Atile + q * 8), 16, 0, 0);
        __builtin_amdgcn_global_load_lds(
            (const __attribute__((address_space(1))) void*)srcB,
            (__attribute__((address_space(3))) void*)(Btile + q * 8), 16, 0, 0);
    }
    __syncthreads();

    int w = tid >> 6;            // wave 0..3
    int lane = tid & 63;
    int wr = w >> 1;             // wave row half
    int wcol = w & 1;            // wave col half
    int lrow = lane & 15;
    int quad = lane >> 4;

    frag_cd acc[4][4];
#pragma unroll
    for (int p = 0; p < 4; ++p)
#pragma unroll
        for (int q = 0; q < 4; ++q) {
            acc[p][q][0] = 0.f; acc[p][q][1] = 0.f; acc[p][q][2] = 0.f; acc[p][q][3] = 0.f;
        }

#pragma unroll
    for (int kk = 0; kk < 4; ++kk) {     // k-chunks of 32
        int ko = kk * 4 + quad;          // this lane's k-octet
        frag_ab af[4], bf[4];
#pragma unroll
        for (int p = 0; p < 4; ++p) {
            int r = wr * 64 + p * 16 + lrow;
            int chunk = r * 16 + (ko ^ (r & 15));
            af[p] = *(const frag_ab*)&Atile[chunk * 8];
        }
#pragma unroll
        for (int q = 0; q < 4; ++q) {
            int n = wcol * 64 + q * 16 + lrow;
            int chunk = n * 16 + (ko ^ (n & 15));
            bf[q] = *(const frag_ab*)&Btile[chunk * 8];
        }
#pragma unroll
        for (int p = 0; p < 4; ++p)
#pragma unroll
            for (int q = 0; q < 4; ++q)
                acc[p][q] = __builtin_amdgcn_mfma_f32_16x16x32_bf16(af[p], bf[q], acc[p][q], 0, 0, 0);
    }

    // epilogue: C/D layout col = lane&15, row = quad*4 + reg
    long rowbase = (long)rb * 128;
#pragma unroll
    for (int p = 0; p < 4; ++p) {
        int trow0 = wr * 64 + p * 16 + quad * 4;
#pragma unroll
        for (int reg = 0; reg < 4; ++reg) {
            long row = rowbase + trow0 + reg;
            float ci = wc[row * 128 + cb];
            float gi = wgv[row * 128 + cb];
            float* orow = out + JACOFF + row * 16384 + (long)cb * 128;
#pragma unroll
            for (int q = 0; q < 4; ++q) {
                int tcol = wcol * 64 + q * 16 + lrow;
                float v = ci * acc[p][q][reg];
                if (tcol == cb) v += gi;
                orow[tcol] = v;
            }
        }
    }
}

// ---------- dh_dWh[b,i,p,q] = u[b,i] * hF[b,p] * dF[b,q] * Wgate[q,i] ----------
__global__ __launch_bounds__(128) void dhdw_kernel(const float* __restrict__ Wgate,
                                                   const float* __restrict__ dF,
                                                   const float* __restrict__ uF,
                                                   const float* __restrict__ hF,
                                                   float* __restrict__ out)
{
    int blk = blockIdx.x;               // b*128 + i
    int b = blk >> 7, i = blk & 127;
    int q = threadIdx.x;
    float u = uF[b * 128 + i];
    float w = dF[b * 128 + q] * Wgate[q * 128 + i];
    float uw = u * w;
    const float* hrow = hF + b * 128;
    float* dst = out + DHWOFF + ((long)(b * 128 + i)) * 16384 + q;
#pragma unroll 4
    for (int p = 0; p < 128; ++p) {
        dst[p * 128] = uw * hrow[p];    // hrow[p] is wave-uniform -> s_load
    }
}

extern "C" void kernel_launch(void* const* d_in, const int* in_sizes, int n_in,
                              void* d_out, int out_size, void* d_ws, size_t ws_size,
                              hipStream_t stream)
{
    (void)in_sizes; (void)n_in; (void)out_size; (void)ws_size;
    const float* x     = (const float*)d_in[0];
    const float* h0    = (const float*)d_in[1];
    const float* Wx    = (const float*)d_in[2];
    const float* Wgate = (const float*)d_in[3];
    const float* Wh    = (const float*)d_in[4];
    float* out = (float*)d_out;
    float* ws  = (float*)d_ws;

    // workspace layout (floats), ~14.9 MB total.
    // xw is dead after scan; PT (1M floats as 2M bf16) reuses its space (pk runs after scan).
    float* xw  = ws;                         // 1048576  [b][t][i]
    short* PT  = (short*)ws;                 // 2097152 bf16 == same 1048576 floats
    float* whT = ws + 1048576;               // 16384
    float* wgT = ws + 1064960;               // 16384
    float* wxT = ws + 1081344;               // 8192
    float* wgv = ws + 1089536;               // 1048576  [t*32+b][i]
    float* wc  = ws + 2138112;               // 1048576
    float* wdF = ws + 3186688;               // 4096
    float* wuF = ws + 3190784;               // 4096
    float* whF = ws + 3194880;               // 4096
    short* Abf = (short*)(ws + 3198976);     // 1048576 bf16 (524288 floats) [t*32+b][k]

    prep_kernel<<<160, 256, 0, stream>>>(Wh, Wgate, Wx, whT, wgT, wxT);
    xw_kernel<<<8192, 128, 0, stream>>>(x, wxT, xw);
    scan_kernel<<<32, 128, 0, stream>>>(xw, h0, whT, wgT, out, Abf, wgv, wc, wdF, wuF, whF);
    pk_kernel<<<1024, 256, 0, stream>>>(Wgate, Wh, PT);   // overwrites xw region (scan done)
    jacmm_kernel<<<8192, 256, 0, stream>>>(Abf, PT, wgv, wc, out);
    dhdw_kernel<<<4096, 128, 0, stream>>>(Wgate, wdF, wuF, whF, out);
}

// Round 3
// 1135.641 us; speedup vs baseline: 1.6267x; 1.1884x over previous
//
#include <hip/hip_runtime.h>

// Problem constants: B=32, T=256, IN=64, D=128
// Outputs (fp32, concatenated): h_final[32,128] | y[32,256,128] | jacs[256,32,128,128] | dh_dWh[32,128,128,128]
// out offsets: 0, 4096, 1052672, 135270400  (total 202379264)

#define JACOFF 1052672L
#define DHWOFF 135270400L

typedef __attribute__((ext_vector_type(8))) short frag_ab;   // 8 bf16 (4 VGPRs)
typedef __attribute__((ext_vector_type(4))) float frag_cd;   // 4 fp32

__device__ __forceinline__ short f2bf(float f) {
    unsigned u = __builtin_bit_cast(unsigned, f);
    unsigned r = (u + 0x7fffu + ((u >> 16) & 1u)) >> 16;     // RNE
    return (short)r;
}

// ---------- prep (blocks 0..127): transpose Wh, Wgate ; xw (blocks 128+): x@Wx ----------
__global__ __launch_bounds__(256) void prep_xw_kernel(
    const float* __restrict__ Wh, const float* __restrict__ Wg,
    const float* __restrict__ x, const float* __restrict__ Wx,
    float* __restrict__ whT, float* __restrict__ wgT, float* __restrict__ xw)
{
    int blk = blockIdx.x;
    int tid = threadIdx.x;
    if (blk < 128) {
        int idx = blk * 256 + tid;               // 0..32767
        if (idx < 16384) {                       // WhT[i][k] = Wh[k][i]
            int k = idx >> 7, i = idx & 127;
            whT[i * 128 + k] = Wh[idx];
        } else {                                 // WgT[i][k] = Wgate[k][i]
            int r = idx - 16384;
            int k = r >> 7, i = r & 127;
            wgT[i * 128 + k] = Wg[r];
        }
        return;
    }
    // xw path: 2 (b,t) rows per block
    __shared__ float xs[2][64];
    int sub = tid >> 7;                          // 0/1
    int bt = (blk - 128) * 2 + sub;
    int i = tid & 127;
    if (i < 64) xs[sub][i] = x[bt * 64 + i];
    __syncthreads();
    float acc = 0.f;
#pragma unroll
    for (int m = 0; m < 64; ++m)
        acc += xs[sub][m] * Wx[m * 128 + i];     // Wx row: coalesced across i, L1-hot
    xw[bt * 128 + i] = acc;
}

// ---------- scan (blocks 0..31) + pk (blocks 32..1055) fused ----------
// scan: one block per batch, 256 threads, lane-paired 2-way k-split.
//   thread (i = tid>>1, half = tid&1) computes half the K=128 dot; pair combines via shfl_xor(1).
// pk: PT[col][k] = bf16(Wgate[k][i] * Wh[j][k]), col = i*128+j. 16 cols/block.
__global__ __launch_bounds__(256, 1) void scan_pk_kernel(
    const float* __restrict__ xw, const float* __restrict__ h0,
    const float* __restrict__ whT, const float* __restrict__ wgT,
    const float* __restrict__ Wgate, const float* __restrict__ Wh,
    float* __restrict__ out,
    short* __restrict__ Abf, float* __restrict__ wgv, float* __restrict__ wc,
    float* __restrict__ wdF, float* __restrict__ wuF, float* __restrict__ whF,
    short* __restrict__ PT)
{
    int tid = threadIdx.x;
    if (blockIdx.x >= 32) {
        // ---- pk path ----
        int c = (blockIdx.x - 32) * 16 + (tid >> 4);
        int k0 = (tid & 15) * 8;
        int i = c >> 7, j = c & 127;
        short v[8];
#pragma unroll
        for (int m = 0; m < 8; ++m) {
            float wg = Wgate[(k0 + m) * 128 + i];
            float wh = Wh[j * 128 + k0 + m];
            v[m] = f2bf(wg * wh);
        }
        *(frag_ab*)(PT + (long)c * 128 + k0) = *(frag_ab*)v;
        return;
    }

    // ---- scan path ----
    const int b = blockIdx.x;
    const int i = tid >> 1, half = tid & 1;
    __shared__ float hbuf[2][128];
    __shared__ float abuf[128];
    float wh[64], wgc[64];
    {
        const float* whr = whT + i * 128 + half * 64;   // half of column i of Wh
        const float* wgr = wgT + i * 128 + half * 64;
#pragma unroll
        for (int k = 0; k < 64; k += 4) {
            float4 a4 = *(const float4*)(whr + k);
            wh[k] = a4.x; wh[k + 1] = a4.y; wh[k + 2] = a4.z; wh[k + 3] = a4.w;
            float4 b4 = *(const float4*)(wgr + k);
            wgc[k] = b4.x; wgc[k + 1] = b4.y; wgc[k + 2] = b4.z; wgc[k + 3] = b4.w;
        }
    }
    if (half == 0) hbuf[0][i] = h0[b * 128 + i];
    __syncthreads();

    const float inv_sqrt2 = 0.70710678118654752f;
    const float inv_sqrt2pi = 0.39894228040143268f;

    float xwv = xw[(b * 256 + 0) * 128 + i];

    for (int t = 0; t < 256; ++t) {
        int p = t & 1;
        int tn = (t < 255) ? t + 1 : 255;
        float xwn = xw[(b * 256 + tn) * 128 + i];          // prefetch next step

        float s0 = 0.f, s1 = 0.f, s2 = 0.f, s3 = 0.f;
        const float* hb = &hbuf[p][half * 64];
#pragma unroll
        for (int k = 0; k < 64; k += 4) {
            float4 h4 = *(const float4*)(hb + k);
            s0 += h4.x * wh[k];
            s1 += h4.y * wh[k + 1];
            s2 += h4.z * wh[k + 2];
            s3 += h4.w * wh[k + 3];
        }
        float s = (s0 + s1) + (s2 + s3);
        s += __shfl_xor(s, 1);
        float pre = xwv + s;

        float cdf = 0.5f * (1.0f + erff(pre * inv_sqrt2));
        float a = pre * cdf;                                   // exact gelu
        float dval = cdf + pre * inv_sqrt2pi * expf(-0.5f * pre * pre);  // gelu'

        long tb = (long)(t * 32 + b) * 128 + i;
        if (half == 0) {
            Abf[tb] = f2bf(dval);
            abuf[i] = a;
        }
        __syncthreads();                                       // (1) abuf visible

        float r0 = 0.f, r1 = 0.f, r2 = 0.f, r3 = 0.f;
        const float* ab = &abuf[half * 64];
#pragma unroll
        for (int k = 0; k < 64; k += 4) {
            float4 a4 = *(const float4*)(ab + k);
            r0 += a4.x * wgc[k];
            r1 += a4.y * wgc[k + 1];
            r2 += a4.z * wgc[k + 2];
            r3 += a4.w * wgc[k + 3];
        }
        float r = (r0 + r1) + (r2 + r3);
        r += __shfl_xor(r, 1);
        float g = 1.0f / (1.0f + expf(-r));
        float hp = hbuf[p][i];
        float c = (hp - 1.0f) * g * (1.0f - g);
        float hn = g * hp + 1.0f - g;
        if (half == 0) {
            hbuf[p ^ 1][i] = hn;
            wgv[tb] = g;
            wc[tb] = c;
            out[4096 + (b * 256 + t) * 128 + i] = hn;          // y
        }
        xwv = xwn;
        __syncthreads();                                       // (2) new h visible
    }

    float hfin = hbuf[0][i];                                   // T even -> final state in buf 0
    if (half == 0) {
        out[b * 128 + i] = hfin;                               // h_final
        whF[b * 128 + i] = hfin;
    }

    // extra evaluation at (x_last, h_final) for dh_dWh
    {
        float s0 = 0.f, s1 = 0.f, s2 = 0.f, s3 = 0.f;
        const float* hb = &hbuf[0][half * 64];
#pragma unroll
        for (int k = 0; k < 64; k += 4) {
            float4 h4 = *(const float4*)(hb + k);
            s0 += h4.x * wh[k];
            s1 += h4.y * wh[k + 1];
            s2 += h4.z * wh[k + 2];
            s3 += h4.w * wh[k + 3];
        }
        float s = (s0 + s1) + (s2 + s3);
        s += __shfl_xor(s, 1);
        float pre = xwv + s;                                   // xwv == xw[b, 255]
        float cdf = 0.5f * (1.0f + erff(pre * inv_sqrt2));
        float a = pre * cdf;
        float dval = cdf + pre * inv_sqrt2pi * expf(-0.5f * pre * pre);
        if (half == 0) {
            wdF[b * 128 + i] = dval;
            abuf[i] = a;
        }
        __syncthreads();
        float r0 = 0.f, r1 = 0.f, r2 = 0.f, r3 = 0.f;
        const float* ab = &abuf[half * 64];
#pragma unroll
        for (int k = 0; k < 64; k += 4) {
            float4 a4 = *(const float4*)(ab + k);
            r0 += a4.x * wgc[k];
            r1 += a4.y * wgc[k + 1];
            r2 += a4.z * wgc[k + 2];
            r3 += a4.w * wgc[k + 3];
        }
        float r = (r0 + r1) + (r2 + r3);
        r += __shfl_xor(r, 1);
        float g = 1.0f / (1.0f + expf(-r));
        if (half == 0) wuF[b * 128 + i] = (hfin - 1.0f) * g * (1.0f - g);
    }
}

// ---------- jacs as one GEMM: C[row=tb][col=i*128+j] = sum_k Abf[row][k] * PT[col][k] ----------
// epilogue: out = c[row, cb]*acc + (j==cb)*g[row, cb], where cb = col block = i.
// 128x128 C-tile per 256-thread block; bf16 MFMA 16x16x32; K=128 single pass.
// LDS tiles stored as XOR-swizzled 16B chunks: chunk(r, ko) lives at index r*16 + (ko ^ (r&15)).
__global__ __launch_bounds__(256) void jacmm_kernel(
    const short* __restrict__ Abf,   // [8192][128] bf16
    const short* __restrict__ PT,    // [16384][128] bf16
    const float* __restrict__ wgv,   // [8192][128]
    const float* __restrict__ wc,    // [8192][128]
    float* __restrict__ out)
{
    __shared__ short Atile[128 * 128];   // 32 KB
    __shared__ short Btile[128 * 128];   // 32 KB

    int bx = blockIdx.x;
    int rb = bx & 63;        // row block: tb in [rb*128, rb*128+128)
    int cb = bx >> 6;        // col block = i (0..127)
    int tid = threadIdx.x;

    const short* Ag = Abf + (long)rb * (128 * 128);
    const short* Bg = PT + (long)cb * (128 * 128);

    // stage both tiles via global_load_lds width=16, swizzled via per-lane global source
#pragma unroll
    for (int e = 0; e < 8; ++e) {
        int q = e * 256 + tid;           // LDS chunk slot 0..2047 (lane-contiguous)
        int r = q >> 4;
        int s = q & 15;
        int ko = s ^ (r & 15);           // which global k-octet lands in this slot
        const short* srcA = Ag + r * 128 + ko * 8;
        const short* srcB = Bg + r * 128 + ko * 8;
        __builtin_amdgcn_global_load_lds(
            (const __attribute__((address_space(1))) void*)srcA,
            (__attribute__((address_space(3))) void*)(Atile + q * 8), 16, 0, 0);
        __builtin_amdgcn_global_load_lds(
            (const __attribute__((address_space(1))) void*)srcB,
            (__attribute__((address_space(3))) void*)(Btile + q * 8), 16, 0, 0);
    }
    __syncthreads();

    int w = tid >> 6;            // wave 0..3
    int lane = tid & 63;
    int wr = w >> 1;             // wave row half
    int wcol = w & 1;            // wave col half
    int lrow = lane & 15;
    int quad = lane >> 4;

    frag_cd acc[4][4];
#pragma unroll
    for (int p = 0; p < 4; ++p)
#pragma unroll
        for (int q = 0; q < 4; ++q) {
            acc[p][q][0] = 0.f; acc[p][q][1] = 0.f; acc[p][q][2] = 0.f; acc[p][q][3] = 0.f;
        }

#pragma unroll
    for (int kk = 0; kk < 4; ++kk) {     // k-chunks of 32
        int ko = kk * 4 + quad;          // this lane's k-octet
        frag_ab af[4], bf[4];
#pragma unroll
        for (int p = 0; p < 4; ++p) {
            int r = wr * 64 + p * 16 + lrow;
            int chunk = r * 16 + (ko ^ (r & 15));
            af[p] = *(const frag_ab*)&Atile[chunk * 8];
        }
#pragma unroll
        for (int q = 0; q < 4; ++q) {
            int n = wcol * 64 + q * 16 + lrow;
            int chunk = n * 16 + (ko ^ (n & 15));
            bf[q] = *(const frag_ab*)&Btile[chunk * 8];
        }
#pragma unroll
        for (int p = 0; p < 4; ++p)
#pragma unroll
            for (int q = 0; q < 4; ++q)
                acc[p][q] = __builtin_amdgcn_mfma_f32_16x16x32_bf16(af[p], bf[q], acc[p][q], 0, 0, 0);
    }

    // epilogue: C/D layout col = lane&15, row = quad*4 + reg
    long rowbase = (long)rb * 128;
#pragma unroll
    for (int p = 0; p < 4; ++p) {
        int trow0 = wr * 64 + p * 16 + quad * 4;
#pragma unroll
        for (int reg = 0; reg < 4; ++reg) {
            long row = rowbase + trow0 + reg;
            float ci = wc[row * 128 + cb];
            float gi = wgv[row * 128 + cb];
            float* orow = out + JACOFF + row * 16384 + (long)cb * 128;
#pragma unroll
            for (int q = 0; q < 4; ++q) {
                int tcol = wcol * 64 + q * 16 + lrow;
                float v = ci * acc[p][q][reg];
                if (tcol == cb) v += gi;
                orow[tcol] = v;
            }
        }
    }
}

// ---------- dh_dWh[b,i,p,q] = u[b,i] * hF[b,p] * dF[b,q] * Wgate[q,i] ----------
// one block per (b,i); thread owns 4 consecutive q and 16 p's -> float4 stores
__global__ __launch_bounds__(256) void dhdw_kernel(const float* __restrict__ Wgate,
                                                   const float* __restrict__ dF,
                                                   const float* __restrict__ uF,
                                                   const float* __restrict__ hF,
                                                   float* __restrict__ out)
{
    int blk = blockIdx.x;               // b*128 + i
    int b = blk >> 7, i = blk & 127;
    int tid = threadIdx.x;
    __shared__ float hs[128], dsh[128];
    if (tid < 128) {
        hs[tid] = hF[b * 128 + tid];
        dsh[tid] = dF[b * 128 + tid];
    }
    __syncthreads();
    float u = uF[b * 128 + i];
    int q0 = (tid & 31) * 4, p0 = (tid >> 5) * 16;
    float w0 = u * dsh[q0 + 0] * Wgate[(q0 + 0) * 128 + i];
    float w1 = u * dsh[q0 + 1] * Wgate[(q0 + 1) * 128 + i];
    float w2 = u * dsh[q0 + 2] * Wgate[(q0 + 2) * 128 + i];
    float w3 = u * dsh[q0 + 3] * Wgate[(q0 + 3) * 128 + i];
    float* dst = out + DHWOFF + (long)(b * 128 + i) * 16384;
#pragma unroll
    for (int pp = 0; pp < 16; ++pp) {
        float hp = hs[p0 + pp];
        *(float4*)(dst + (p0 + pp) * 128 + q0) = make_float4(hp * w0, hp * w1, hp * w2, hp * w3);
    }
}

extern "C" void kernel_launch(void* const* d_in, const int* in_sizes, int n_in,
                              void* d_out, int out_size, void* d_ws, size_t ws_size,
                              hipStream_t stream)
{
    (void)in_sizes; (void)n_in; (void)out_size; (void)ws_size;
    const float* x     = (const float*)d_in[0];
    const float* h0    = (const float*)d_in[1];
    const float* Wx    = (const float*)d_in[2];
    const float* Wgate = (const float*)d_in[3];
    const float* Wh    = (const float*)d_in[4];
    float* out = (float*)d_out;
    float* ws  = (float*)d_ws;

    // workspace layout (floats), ~19 MB total, no aliasing (pk runs concurrently with scan)
    float* xw  = ws;                         // 1048576  [b][t][i]
    float* whT = ws + 1048576;               // 16384
    float* wgT = ws + 1064960;               // 16384
    float* wgv = ws + 1081344;               // 1048576  [t*32+b][i]
    float* wc  = ws + 2129920;               // 1048576
    float* wdF = ws + 3178496;               // 4096
    float* wuF = ws + 3182592;               // 4096
    float* whF = ws + 3186688;               // 4096
    short* Abf = (short*)(ws + 3190784);     // 1048576 bf16 (524288 floats) [t*32+b][k]
    short* PT  = (short*)(ws + 3715072);     // 2097152 bf16 (1048576 floats) [col][k]

    prep_xw_kernel<<<4224, 256, 0, stream>>>(Wh, Wgate, x, Wx, whT, wgT, xw);
    scan_pk_kernel<<<1056, 256, 0, stream>>>(xw, h0, whT, wgT, Wgate, Wh, out,
                                             Abf, wgv, wc, wdF, wuF, whF, PT);
    jacmm_kernel<<<8192, 256, 0, stream>>>(Abf, PT, wgv, wc, out);
    dhdw_kernel<<<4096, 256, 0, stream>>>(Wgate, wdF, wuF, whF, out);
}

// Round 4
// 1084.947 us; speedup vs baseline: 1.7027x; 1.0467x over previous
//
#include <hip/hip_runtime.h>

// Problem constants: B=32, T=256, IN=64, D=128
// Outputs (fp32, concatenated): h_final[32,128] | y[32,256,128] | jacs[256,32,128,128] | dh_dWh[32,128,128,128]
// out offsets: 0, 4096, 1052672, 135270400  (total 202379264)

#define JACOFF 1052672L
#define DHWOFF 135270400L

typedef __attribute__((ext_vector_type(8))) short frag_ab;   // 8 bf16 (4 VGPRs)
typedef __attribute__((ext_vector_type(4))) float frag_cd;   // 4 fp32

__device__ __forceinline__ short f2bf(float f) {
    unsigned u = __builtin_bit_cast(unsigned, f);
    unsigned r = (u + 0x7fffu + ((u >> 16) & 1u)) >> 16;     // RNE
    return (short)r;
}

// ---------- prep (blocks 0..127): transpose Wh, Wgate ; xw (blocks 128+): x@Wx ----------
__global__ __launch_bounds__(256) void prep_xw_kernel(
    const float* __restrict__ Wh, const float* __restrict__ Wg,
    const float* __restrict__ x, const float* __restrict__ Wx,
    float* __restrict__ whT, float* __restrict__ wgT, float* __restrict__ xw)
{
    int blk = blockIdx.x;
    int tid = threadIdx.x;
    if (blk < 128) {
        int idx = blk * 256 + tid;               // 0..32767
        if (idx < 16384) {                       // WhT[i][k] = Wh[k][i]
            int k = idx >> 7, i = idx & 127;
            whT[i * 128 + k] = Wh[idx];
        } else {                                 // WgT[i][k] = Wgate[k][i]
            int r = idx - 16384;
            int k = r >> 7, i = r & 127;
            wgT[i * 128 + k] = Wg[r];
        }
        return;
    }
    // xw path: 2 (b,t) rows per block
    __shared__ float xs[2][64];
    int sub = tid >> 7;                          // 0/1
    int bt = (blk - 128) * 2 + sub;
    int i = tid & 127;
    if (i < 64) xs[sub][i] = x[bt * 64 + i];
    __syncthreads();
    float acc = 0.f;
#pragma unroll
    for (int m = 0; m < 64; ++m)
        acc += xs[sub][m] * Wx[m * 128 + i];     // Wx row: coalesced across i, L1-hot
    xw[bt * 128 + i] = acc;
}

// ---------- scan (blocks 0..31, 512 thr, 4-way k-split) + pk (blocks 32..543) fused ----------
// scan: thread (i = tid>>2, qtr = tid&3) computes a 32-wide partial dot; combine via
//   shfl_xor(1) + shfl_xor(2) (lane groups of 4 never cross the 64-lane wave boundary).
// pk: PT[col][k] = bf16(Wgate[k][i] * Wh[j][k]), col = i*128+j. 32 cols/block @512 thr.
__global__ __launch_bounds__(512, 1) void scan_pk_kernel(
    const float* __restrict__ xw, const float* __restrict__ h0,
    const float* __restrict__ whT, const float* __restrict__ wgT,
    const float* __restrict__ Wgate, const float* __restrict__ Wh,
    float* __restrict__ out,
    short* __restrict__ Abf, float* __restrict__ wgv, float* __restrict__ wc,
    float* __restrict__ wdF, float* __restrict__ wuF, float* __restrict__ whF,
    short* __restrict__ PT)
{
    int tid = threadIdx.x;
    if (blockIdx.x >= 32) {
        // ---- pk path ----
        int c = (blockIdx.x - 32) * 32 + (tid >> 4);
        int k0 = (tid & 15) * 8;
        int i = c >> 7, j = c & 127;
        short v[8];
#pragma unroll
        for (int m = 0; m < 8; ++m) {
            float wg = Wgate[(k0 + m) * 128 + i];
            float wh = Wh[j * 128 + k0 + m];
            v[m] = f2bf(wg * wh);
        }
        *(frag_ab*)(PT + (long)c * 128 + k0) = *(frag_ab*)v;
        return;
    }

    // ---- scan path ----
    const int b = blockIdx.x;
    const int i = tid >> 2, qtr = tid & 3;
    __shared__ float hbuf[2][128];
    __shared__ float abuf[128];
    float wh[32], wgc[32];
    {
        const float* whr = whT + i * 128 + qtr * 32;   // quarter of column i of Wh
        const float* wgr = wgT + i * 128 + qtr * 32;
#pragma unroll
        for (int k = 0; k < 32; k += 4) {
            float4 a4 = *(const float4*)(whr + k);
            wh[k] = a4.x; wh[k + 1] = a4.y; wh[k + 2] = a4.z; wh[k + 3] = a4.w;
            float4 b4 = *(const float4*)(wgr + k);
            wgc[k] = b4.x; wgc[k + 1] = b4.y; wgc[k + 2] = b4.z; wgc[k + 3] = b4.w;
        }
    }
    if (qtr == 0) hbuf[0][i] = h0[b * 128 + i];
    __syncthreads();

    const float inv_sqrt2 = 0.70710678118654752f;
    const float inv_sqrt2pi = 0.39894228040143268f;

    float xwv = xw[(b * 256 + 0) * 128 + i];

    for (int t = 0; t < 256; ++t) {
        int p = t & 1;
        int tn = (t < 255) ? t + 1 : 255;
        float xwn = xw[(b * 256 + tn) * 128 + i];          // prefetch next step

        float s0 = 0.f, s1 = 0.f, s2 = 0.f, s3 = 0.f;
        const float* hb = &hbuf[p][qtr * 32];
#pragma unroll
        for (int k = 0; k < 32; k += 4) {
            float4 h4 = *(const float4*)(hb + k);
            s0 += h4.x * wh[k];
            s1 += h4.y * wh[k + 1];
            s2 += h4.z * wh[k + 2];
            s3 += h4.w * wh[k + 3];
        }
        float s = (s0 + s1) + (s2 + s3);
        s += __shfl_xor(s, 1);
        s += __shfl_xor(s, 2);
        float pre = xwv + s;

        float cdf = 0.5f * (1.0f + erff(pre * inv_sqrt2));
        float a = pre * cdf;                                   // exact gelu
        float dval = cdf + pre * inv_sqrt2pi * expf(-0.5f * pre * pre);  // gelu'

        long tb = (long)(t * 32 + b) * 128 + i;
        if (qtr == 0) {
            Abf[tb] = f2bf(dval);
            abuf[i] = a;
        }
        __syncthreads();                                       // (1) abuf visible

        float r0 = 0.f, r1 = 0.f, r2 = 0.f, r3 = 0.f;
        const float* ab = &abuf[qtr * 32];
#pragma unroll
        for (int k = 0; k < 32; k += 4) {
            float4 a4 = *(const float4*)(ab + k);
            r0 += a4.x * wgc[k];
            r1 += a4.y * wgc[k + 1];
            r2 += a4.z * wgc[k + 2];
            r3 += a4.w * wgc[k + 3];
        }
        float r = (r0 + r1) + (r2 + r3);
        r += __shfl_xor(r, 1);
        r += __shfl_xor(r, 2);
        float g = 1.0f / (1.0f + expf(-r));
        float hp = hbuf[p][i];
        float c = (hp - 1.0f) * g * (1.0f - g);
        float hn = g * hp + 1.0f - g;
        if (qtr == 0) {
            hbuf[p ^ 1][i] = hn;
            wgv[tb] = g;
            wc[tb] = c;
            out[4096 + (b * 256 + t) * 128 + i] = hn;          // y
        }
        xwv = xwn;
        __syncthreads();                                       // (2) new h visible
    }

    float hfin = hbuf[0][i];                                   // T even -> final state in buf 0
    if (qtr == 0) {
        out[b * 128 + i] = hfin;                               // h_final
        whF[b * 128 + i] = hfin;
    }

    // extra evaluation at (x_last, h_final) for dh_dWh
    {
        float s0 = 0.f, s1 = 0.f, s2 = 0.f, s3 = 0.f;
        const float* hb = &hbuf[0][qtr * 32];
#pragma unroll
        for (int k = 0; k < 32; k += 4) {
            float4 h4 = *(const float4*)(hb + k);
            s0 += h4.x * wh[k];
            s1 += h4.y * wh[k + 1];
            s2 += h4.z * wh[k + 2];
            s3 += h4.w * wh[k + 3];
        }
        float s = (s0 + s1) + (s2 + s3);
        s += __shfl_xor(s, 1);
        s += __shfl_xor(s, 2);
        float pre = xwv + s;                                   // xwv == xw[b, 255]
        float cdf = 0.5f * (1.0f + erff(pre * inv_sqrt2));
        float a = pre * cdf;
        float dval = cdf + pre * inv_sqrt2pi * expf(-0.5f * pre * pre);
        if (qtr == 0) {
            wdF[b * 128 + i] = dval;
            abuf[i] = a;
        }
        __syncthreads();
        float r0 = 0.f, r1 = 0.f, r2 = 0.f, r3 = 0.f;
        const float* ab = &abuf[qtr * 32];
#pragma unroll
        for (int k = 0; k < 32; k += 4) {
            float4 a4 = *(const float4*)(ab + k);
            r0 += a4.x * wgc[k];
            r1 += a4.y * wgc[k + 1];
            r2 += a4.z * wgc[k + 2];
            r3 += a4.w * wgc[k + 3];
        }
        float r = (r0 + r1) + (r2 + r3);
        r += __shfl_xor(r, 1);
        r += __shfl_xor(r, 2);
        float g = 1.0f / (1.0f + expf(-r));
        if (qtr == 0) wuF[b * 128 + i] = (hfin - 1.0f) * g * (1.0f - g);
    }
}

// ---------- jacmm (+ fused dhdw): 12288 blocks, pattern [jac,jac,dhdw] ----------
// jac: C[row=tb][col=i*128+j] = sum_k Abf[row][k] * PT[col][k]; epilogue scale+diag.
// dhdw: dh_dWh[b,i,p,q] = u[b,i] * hF[b,p] * dF[b,q] * Wgate[q,i]
__global__ __launch_bounds__(256) void jacmm_dhdw_kernel(
    const short* __restrict__ Abf,   // [8192][128] bf16
    const short* __restrict__ PT,    // [16384][128] bf16
    const float* __restrict__ wgv,   // [8192][128]
    const float* __restrict__ wc,    // [8192][128]
    const float* __restrict__ Wgate,
    const float* __restrict__ dF, const float* __restrict__ uF, const float* __restrict__ hF,
    float* __restrict__ out)
{
    int bx = blockIdx.x;
    int tid = threadIdx.x;
    int grp = bx / 3, rem = bx % 3;

    if (rem == 2) {
        // ---- dhdw path: unit = grp (0..4095) = b*128 + i ----
        __shared__ float hs[128], dsh[128];
        int b = grp >> 7, i = grp & 127;
        if (tid < 128) {
            hs[tid] = hF[b * 128 + tid];
            dsh[tid] = dF[b * 128 + tid];
        }
        __syncthreads();
        float u = uF[b * 128 + i];
        int q0 = (tid & 31) * 4, p0 = (tid >> 5) * 16;
        float w0 = u * dsh[q0 + 0] * Wgate[(q0 + 0) * 128 + i];
        float w1 = u * dsh[q0 + 1] * Wgate[(q0 + 1) * 128 + i];
        float w2 = u * dsh[q0 + 2] * Wgate[(q0 + 2) * 128 + i];
        float w3 = u * dsh[q0 + 3] * Wgate[(q0 + 3) * 128 + i];
        float* dst = out + DHWOFF + (long)grp * 16384;
#pragma unroll
        for (int pp = 0; pp < 16; ++pp) {
            float hp = hs[p0 + pp];
            *(float4*)(dst + (p0 + pp) * 128 + q0) = make_float4(hp * w0, hp * w1, hp * w2, hp * w3);
        }
        return;
    }

    // ---- jac path: tile index = grp*2 + rem (0..8191) ----
    __shared__ short Atile[128 * 128];   // 32 KB
    __shared__ short Btile[128 * 128];   // 32 KB

    int jb = grp * 2 + rem;
    int rb = jb & 63;        // row block: tb in [rb*128, rb*128+128)
    int cb = jb >> 6;        // col block = i (0..127)

    const short* Ag = Abf + (long)rb * (128 * 128);
    const short* Bg = PT + (long)cb * (128 * 128);

    // stage both tiles via global_load_lds width=16, swizzled via per-lane global source
#pragma unroll
    for (int e = 0; e < 8; ++e) {
        int q = e * 256 + tid;           // LDS chunk slot 0..2047 (lane-contiguous)
        int r = q >> 4;
        int s = q & 15;
        int ko = s ^ (r & 15);           // which global k-octet lands in this slot
        const short* srcA = Ag + r * 128 + ko * 8;
        const short* srcB = Bg + r * 128 + ko * 8;
        __builtin_amdgcn_global_load_lds(
            (const __attribute__((address_space(1))) void*)srcA,
            (__attribute__((address_space(3))) void*)(Atile + q * 8), 16, 0, 0);
        __builtin_amdgcn_global_load_lds(
            (const __attribute__((address_space(1))) void*)srcB,
            (__attribute__((address_space(3))) void*)(Btile + q * 8), 16, 0, 0);
    }

    int w = tid >> 6;            // wave 0..3
    int lane = tid & 63;
    int wr = w >> 1;             // wave row half
    int wcol = w & 1;            // wave col half
    int lrow = lane & 15;
    int quad = lane >> 4;

    // prefetch epilogue gathers early (hide ~200-900 cyc latency under MFMA)
    long rowbase = (long)rb * 128;
    float ci[4][4], gi[4][4];
#pragma unroll
    for (int p = 0; p < 4; ++p) {
        int trow0 = wr * 64 + p * 16 + quad * 4;
#pragma unroll
        for (int reg = 0; reg < 4; ++reg) {
            long row = rowbase + trow0 + reg;
            ci[p][reg] = wc[row * 128 + cb];
            gi[p][reg] = wgv[row * 128 + cb];
        }
    }
    __syncthreads();

    frag_cd acc[4][4];
#pragma unroll
    for (int p = 0; p < 4; ++p)
#pragma unroll
        for (int q = 0; q < 4; ++q) {
            acc[p][q][0] = 0.f; acc[p][q][1] = 0.f; acc[p][q][2] = 0.f; acc[p][q][3] = 0.f;
        }

#pragma unroll
    for (int kk = 0; kk < 4; ++kk) {     // k-chunks of 32
        int ko = kk * 4 + quad;          // this lane's k-octet
        frag_ab af[4], bf[4];
#pragma unroll
        for (int p = 0; p < 4; ++p) {
            int r = wr * 64 + p * 16 + lrow;
            int chunk = r * 16 + (ko ^ (r & 15));
            af[p] = *(const frag_ab*)&Atile[chunk * 8];
        }
#pragma unroll
        for (int q = 0; q < 4; ++q) {
            int n = wcol * 64 + q * 16 + lrow;
            int chunk = n * 16 + (ko ^ (n & 15));
            bf[q] = *(const frag_ab*)&Btile[chunk * 8];
        }
#pragma unroll
        for (int p = 0; p < 4; ++p)
#pragma unroll
            for (int q = 0; q < 4; ++q)
                acc[p][q] = __builtin_amdgcn_mfma_f32_16x16x32_bf16(af[p], bf[q], acc[p][q], 0, 0, 0);
    }

    // epilogue: C/D layout col = lane&15, row = quad*4 + reg
#pragma unroll
    for (int p = 0; p < 4; ++p) {
        int trow0 = wr * 64 + p * 16 + quad * 4;
#pragma unroll
        for (int reg = 0; reg < 4; ++reg) {
            long row = rowbase + trow0 + reg;
            float* orow = out + JACOFF + row * 16384 + (long)cb * 128;
#pragma unroll
            for (int q = 0; q < 4; ++q) {
                int tcol = wcol * 64 + q * 16 + lrow;
                float v = ci[p][reg] * acc[p][q][reg];
                if (tcol == cb) v += gi[p][reg];
                orow[tcol] = v;
            }
        }
    }
}

extern "C" void kernel_launch(void* const* d_in, const int* in_sizes, int n_in,
                              void* d_out, int out_size, void* d_ws, size_t ws_size,
                              hipStream_t stream)
{
    (void)in_sizes; (void)n_in; (void)out_size; (void)ws_size;
    const float* x     = (const float*)d_in[0];
    const float* h0    = (const float*)d_in[1];
    const float* Wx    = (const float*)d_in[2];
    const float* Wgate = (const float*)d_in[3];
    const float* Wh    = (const float*)d_in[4];
    float* out = (float*)d_out;
    float* ws  = (float*)d_ws;

    // workspace layout (floats), ~19 MB total, no aliasing (pk runs concurrently with scan)
    float* xw  = ws;                         // 1048576  [b][t][i]
    float* whT = ws + 1048576;               // 16384
    float* wgT = ws + 1064960;               // 16384
    float* wgv = ws + 1081344;               // 1048576  [t*32+b][i]
    float* wc  = ws + 2129920;               // 1048576
    float* wdF = ws + 3178496;               // 4096
    float* wuF = ws + 3182592;               // 4096
    float* whF = ws + 3186688;               // 4096
    short* Abf = (short*)(ws + 3190784);     // 1048576 bf16 (524288 floats) [t*32+b][k]
    short* PT  = (short*)(ws + 3715072);     // 2097152 bf16 (1048576 floats) [col][k]

    prep_xw_kernel<<<4224, 256, 0, stream>>>(Wh, Wgate, x, Wx, whT, wgT, xw);
    scan_pk_kernel<<<544, 512, 0, stream>>>(xw, h0, whT, wgT, Wgate, Wh, out,
                                            Abf, wgv, wc, wdF, wuF, whF, PT);
    jacmm_dhdw_kernel<<<12288, 256, 0, stream>>>(Abf, PT, wgv, wc, Wgate, wdF, wuF, whF, out);
}